// Round 10
// baseline (38.295 us; speedup 1.0000x reference)
//
#include <hip/hip_runtime.h>
#include <cmath>

// Problem constants (fixed by setup_inputs)
constexpr int BN = 16, H = 544, W = 960;
constexpr int OH = 136, OW = 240;
constexpr size_t HW = (size_t)H * W;

constexpr int TOH = 8, TOW = 30, NTH = 17, NTW = 8, MH = 32, MW = 120;
constexpr int GR = 40;     // gray rows: global rows mh0-4 .. mh0+35
constexpr int GS = 132;    // gray row stride (floats)
constexpr int NT = 5;      // 40 rows x 32 quads = 1280 = 5*256 tasks/thread
constexpr int NTILE = BN * NTH * NTW;   // 2176
constexpr int GRID = NTILE / 2;         // 1088; block does tile blk and blk+1088
                                        // (1088 % 136 == 0 -> same (th,tw), image b and b+8)

__global__ __launch_bounds__(256)
void edge_fused(const float* __restrict__ in, float* __restrict__ out,
                float gn0, float gn1, float gn2)
{
    __shared__ float gray[GR * GS];   // 21120 B

    const int tid = threadIdx.x;
    const int blk = blockIdx.x;
    const int tw = blk & 7;
    const int th = (blk >> 3) % NTH;
    const int b0 = blk / (NTH * NTW);          // 0..7 ; second tile: b0+8
    const int mh0 = th * MH, mw0 = tw * MW;
    const float* inb0 = in + (size_t)b0 * 3 * HW;

    float4 Rv[NT], Gv[NT], Bv[NT];

    // ---- issue: 15 unconditional batched float4 loads (unique RGB region) ----
    auto issue = [&](const float* inb) {
        #pragma unroll
        for (int k = 0; k < NT; ++k) {
            const int idx = tid + 256 * k;
            const int r = idx >> 5, c = idx & 31;
            int g = mh0 - 4 + r;                       // row reflect
            g = g < 0 ? -g : (g >= H ? 2 * H - 2 - g : g);
            int gcb = mw0 - 4 + 4 * c;                 // col clamp (edge fixed later)
            gcb = gcb < 0 ? 0 : (gcb > W - 4 ? W - 4 : gcb);
            const float* p = inb + (size_t)g * W + gcb;
            Rv[k] = *reinterpret_cast<const float4*>(p);
            Gv[k] = *reinterpret_cast<const float4*>(p + HW);
            Bv[k] = *reinterpret_cast<const float4*>(p + 2 * HW);
        }
        asm volatile("" ::: "memory");   // pin load issue before subsequent compute
    };

    // ---- convert: regs -> gray LDS; edge quads fixed by intra-wave LDS copy ----
    auto convert = [&]() {
        #pragma unroll
        for (int k = 0; k < NT; ++k) {
            const int idx = tid + 256 * k;
            const int r = idx >> 5, c = idx & 31;
            float4 g;
            g.x = fmaf(0.2989f, Rv[k].x, fmaf(0.587f, Gv[k].x, 0.114f * Bv[k].x));
            g.y = fmaf(0.2989f, Rv[k].y, fmaf(0.587f, Gv[k].y, 0.114f * Bv[k].y));
            g.z = fmaf(0.2989f, Rv[k].z, fmaf(0.587f, Gv[k].z, 0.114f * Bv[k].z));
            g.w = fmaf(0.2989f, Rv[k].w, fmaf(0.587f, Gv[k].w, 0.114f * Bv[k].w));
            *reinterpret_cast<float4*>(&gray[r * GS + 4 * c]) = g;
        }
        if (tw == 0 || tw == NTW - 1) {
            // reflect targets are already-staged interior columns; writers of
            // those quads (tid+-1, tid+-2) are in the SAME wave as the fixer.
            asm volatile("s_waitcnt lgkmcnt(0)" ::: "memory");
            __builtin_amdgcn_sched_barrier(0);
            const int l5 = tid & 31;
            if ((tw == 0 && l5 == 0) || (tw == NTW - 1 && l5 == 31)) {
                const int base  = (tw == 0) ? 0 : 124;   // quad to fix
                const int sbase = (tw == 0) ? 5 : 119;   // reflect source cols
                #pragma unroll
                for (int k = 0; k < NT; ++k) {
                    const int r = (tid >> 5) + 8 * k;
                    float* g = &gray[r * GS];
                    float4 v;
                    v.x = g[sbase + 3]; v.y = g[sbase + 2];
                    v.z = g[sbase + 1]; v.w = g[sbase + 0];
                    *reinterpret_cast<float4*>(&g[base]) = v;
                }
            }
        }
    };

    // ---- phaseB: h-blur row-wise (12->6), v-accumulate, sobel+pool+sigmoid ----
    auto phaseB = [&](float* outb) {
        if (tid < TOH * TOW) {
            const int orow = tid / TOW;
            const int ocol = tid - orow * TOW;
            const int lc0 = 4 * ocol;
            const int rb = 4 * orow + 1;

            float sm6[6][6];
            #pragma unroll
            for (int i = 0; i < 6; ++i)
                #pragma unroll
                for (int j = 0; j < 6; ++j) sm6[i][j] = 0.f;

            const float gk[5] = {gn0, gn1, gn2, gn1, gn0};
            #pragma unroll
            for (int tr = 0; tr < 10; ++tr) {
                const float* p = &gray[(rb + tr) * GS + lc0];
                const float4 u = *reinterpret_cast<const float4*>(p);
                const float4 v = *reinterpret_cast<const float4*>(p + 4);
                const float4 w = *reinterpret_cast<const float4*>(p + 8);
                const float t12[12] = {u.x, u.y, u.z, u.w, v.x, v.y, v.z, v.w,
                                       w.x, w.y, w.z, w.w};
                float h6[6];
                #pragma unroll
                for (int j = 0; j < 6; ++j)
                    h6[j] = fmaf(gn0, t12[1 + j] + t12[5 + j],
                            fmaf(gn1, t12[2 + j] + t12[4 + j], gn2 * t12[3 + j]));
                #pragma unroll
                for (int i = 0; i < 6; ++i) {
                    const int m = tr - i;
                    if (m >= 0 && m < 5) {
                        #pragma unroll
                        for (int j = 0; j < 6; ++j)
                            sm6[i][j] = fmaf(gk[m], h6[j], sm6[i][j]);
                    }
                }
            }

            // sobel zero-padding: zero smooth outside the image
            #pragma unroll
            for (int i = 0; i < 6; ++i) {
                const int hh = mh0 + 4 * orow - 1 + i;
                const float rm = (hh >= 0 && hh < H) ? 1.f : 0.f;
                #pragma unroll
                for (int j = 0; j < 6; ++j) {
                    const int ww = mw0 + 4 * ocol - 1 + j;
                    sm6[i][j] *= rm * ((ww >= 0 && ww < W) ? 1.f : 0.f);
                }
            }

            float acc[4] = {0.f, 0.f, 0.f, 0.f};
            #pragma unroll
            for (int i = 0; i < 4; ++i) {
                #pragma unroll
                for (int j = 0; j < 4; ++j) {
                    const float a00 = sm6[i][j],     a01 = sm6[i][j + 1],     a02 = sm6[i][j + 2];
                    const float a10 = sm6[i + 1][j],                          a12 = sm6[i + 1][j + 2];
                    const float a20 = sm6[i + 2][j], a21 = sm6[i + 2][j + 1], a22 = sm6[i + 2][j + 2];
                    const float gx = (a02 - a00) + 2.f * (a12 - a10) + (a22 - a20);
                    const float gy = (a20 + 2.f * a21 + a22) - (a00 + 2.f * a01 + a02);
                    const float m2 = gx * gx + gy * gy + 1e-6f;
                    float mg;
                    asm("v_sqrt_f32 %0, %1" : "=v"(mg) : "v"(m2));
                    acc[i] += mg;
                }
            }
            const float down = ((acc[0] + acc[1]) + (acc[2] + acc[3])) * (1.f / 16.f);
            const float x = 5.0f * (down - 0.2f);
            const float sg = 1.f / (1.f + __expf(-x));
            outb[(size_t)(mh0 / 4 + orow) * OW + (mw0 / 4 + ocol)] = sg * sg;
        }
    };

    // ---- 2-tile pipeline: T1 loads issued before phaseB(T0) ----
    issue(inb0);
    convert();
    __syncthreads();

    issue(inb0 + (size_t)8 * 3 * HW);              // prefetch tile of image b0+8
    phaseB(out + (size_t)b0 * OH * OW);            // hides T1 load latency
    __syncthreads();

    convert();
    __syncthreads();

    phaseB(out + (size_t)(b0 + 8) * OH * OW);
}

extern "C" void kernel_launch(void* const* d_in, const int* in_sizes, int n_in,
                              void* d_out, int out_size, void* d_ws, size_t ws_size,
                              hipStream_t stream) {
    const float* in = (const float*)d_in[0];
    float* out = (float*)d_out;

    // Gaussian 1D coefficients (separable: outer(g,g)/(sum g)^2), exact in double.
    const double g0 = std::exp(-4.0 / 4.5);  // x=2
    const double g1 = std::exp(-1.0 / 4.5);  // x=1
    const double g2 = 1.0;                   // x=0
    const double S = 2.0 * (g0 + g1) + g2;
    const float gn0 = (float)(g0 / S);
    const float gn1 = (float)(g1 / S);
    const float gn2 = (float)(g2 / S);

    hipLaunchKernelGGL(edge_fused, dim3(GRID), dim3(256), 0, stream,
                       in, out, gn0, gn1, gn2);
}

// Round 11
// 34.025 us; speedup vs baseline: 1.1255x; 1.1255x over previous
//
#include <hip/hip_runtime.h>
#include <cmath>

// Problem constants (fixed by setup_inputs)
constexpr int B = 16, C = 3, H = 544, W = 960;
constexpr int OH = 136, OW = 240;
constexpr size_t HW = (size_t)H * W;

constexpr int TOH = 8, TOW = 30, NTH = 17, NTW = 8, MH = 32, MW = 120;
constexpr int GR = 40;     // gray rows: global rows mh0-4 .. mh0+35 (rows 0,39 pad)
constexpr int GS = 132;    // gray row stride (floats)
constexpr int NT = 5;      // tasks per thread: 40 rows x 32 quads = 1280 = 5*256

// launch_bounds(256,4): 4 waves/EU -> VGPR cap 128 -> 4 blocks/CU co-resident.
// Phase-A peak live = 60 data VGPR, phase-B ~90 -> fits 128 without spills.
__global__ __launch_bounds__(256, 4)
void edge_fused(const float* __restrict__ in, float* __restrict__ out,
                float gn0, float gn1, float gn2)
{
    __shared__ float gray[GR * GS];   // 21120 B -> 7 blocks/CU LDS-wise

    const int tid = threadIdx.x;
    const int blk = blockIdx.x;
    const int tw = blk % NTW;
    const int th = (blk / NTW) % NTH;
    const int b  = blk / (NTW * NTH);
    const int mh0 = th * MH, mw0 = tw * MW;
    const float* inb = in + (size_t)b * C * HW;

    // ---- phase A: load unique RGB region once (batched, unconditional),
    //      convert to gray in LDS. gray[r][lc] <-> global (mh0-4+r, mw0-4+lc).
    float4 Rv[NT], Gv[NT], Bv[NT];
    #pragma unroll
    for (int k = 0; k < NT; ++k) {
        const int idx = tid + 256 * k;
        const int r = idx >> 5;          // /32 quads per row
        const int c = idx & 31;
        int g = mh0 - 4 + r;             // row reflect (always valid)
        g = g < 0 ? -g : (g >= H ? 2 * H - 2 - g : g);
        int gcb = mw0 - 4 + 4 * c;       // col clamp keeps alignment; edge quads fixed below
        gcb = gcb < 0 ? 0 : (gcb > W - 4 ? W - 4 : gcb);
        const float* p = inb + (size_t)g * W + gcb;
        Rv[k] = *reinterpret_cast<const float4*>(p);
        Gv[k] = *reinterpret_cast<const float4*>(p + HW);
        Bv[k] = *reinterpret_cast<const float4*>(p + 2 * HW);
    }
    #pragma unroll
    for (int k = 0; k < NT; ++k) {
        const int idx = tid + 256 * k;
        const int r = idx >> 5;
        const int c = idx & 31;
        float4 g;
        g.x = fmaf(0.2989f, Rv[k].x, fmaf(0.587f, Gv[k].x, 0.114f * Bv[k].x));
        g.y = fmaf(0.2989f, Rv[k].y, fmaf(0.587f, Gv[k].y, 0.114f * Bv[k].y));
        g.z = fmaf(0.2989f, Rv[k].z, fmaf(0.587f, Gv[k].z, 0.114f * Bv[k].z));
        g.w = fmaf(0.2989f, Rv[k].w, fmaf(0.587f, Gv[k].w, 0.114f * Bv[k].w));
        const bool edgeq = (tw == 0 && c == 0) || (tw == NTW - 1 && c == 31);
        if (!edgeq)
            *reinterpret_cast<float4*>(&gray[r * GS + 4 * c]) = g;
    }
    // column-reflect fixup for the 40 edge quads (only writer of those quads)
    if ((tw == 0 || tw == NTW - 1) && tid < GR) {
        const int r = tid;
        const int c = (tw == 0) ? 0 : 31;
        int g = mh0 - 4 + r;
        g = g < 0 ? -g : (g >= H ? 2 * H - 2 - g : g);
        float4 gv;
        float* gp = &gv.x;
        #pragma unroll
        for (int m = 0; m < 4; ++m) {
            int gc = mw0 - 4 + 4 * c + m;
            gc = gc < 0 ? -gc : (gc >= W ? 2 * W - 2 - gc : gc);
            const float* p = inb + (size_t)g * W + gc;
            gp[m] = 0.2989f * p[0] + 0.587f * p[HW] + 0.114f * p[2 * HW];
        }
        *reinterpret_cast<float4*>(&gray[r * GS + 4 * c]) = gv;
    }
    __syncthreads();

    // ---- phase B: per LDS row h-blur (12->6), v-accumulate into sm6, then
    //      sobel + pool + sigmoid. Low register footprint. ----
    if (tid < TOH * TOW) {
        const int orow = tid / TOW;
        const int ocol = tid - orow * TOW;
        const int lc0 = 4 * ocol;        // gray local col base (reads lc0..lc0+11)
        const int rb = 4 * orow + 1;     // gray local row base (reads rb..rb+9)

        float sm6[6][6];                 // smooth rows i=0..5, cols j=0..5
        #pragma unroll
        for (int i = 0; i < 6; ++i)
            #pragma unroll
            for (int j = 0; j < 6; ++j) sm6[i][j] = 0.f;

        const float gk[5] = {gn0, gn1, gn2, gn1, gn0};
        #pragma unroll
        for (int tr = 0; tr < 10; ++tr) {
            const float* p = &gray[(rb + tr) * GS + lc0];
            const float4 u = *reinterpret_cast<const float4*>(p);
            const float4 v = *reinterpret_cast<const float4*>(p + 4);
            const float4 w = *reinterpret_cast<const float4*>(p + 8);
            const float t12[12] = {u.x, u.y, u.z, u.w, v.x, v.y, v.z, v.w,
                                   w.x, w.y, w.z, w.w};
            float h6[6];                 // h-blurred gray for this row
            #pragma unroll
            for (int j = 0; j < 6; ++j)
                h6[j] = fmaf(gn0, t12[1 + j] + t12[5 + j],
                        fmaf(gn1, t12[2 + j] + t12[4 + j], gn2 * t12[3 + j]));
            #pragma unroll
            for (int i = 0; i < 6; ++i) {
                const int m = tr - i;
                if (m >= 0 && m < 5) {
                    #pragma unroll
                    for (int j = 0; j < 6; ++j)
                        sm6[i][j] = fmaf(gk[m], h6[j], sm6[i][j]);
                }
            }
        }

        // sobel zero-padding: zero smooth outside the image
        #pragma unroll
        for (int i = 0; i < 6; ++i) {
            const int hh = mh0 + 4 * orow - 1 + i;
            const float rm = (hh >= 0 && hh < H) ? 1.f : 0.f;
            #pragma unroll
            for (int j = 0; j < 6; ++j) {
                const int ww = mw0 + 4 * ocol - 1 + j;
                sm6[i][j] *= rm * ((ww >= 0 && ww < W) ? 1.f : 0.f);
            }
        }

        // sobel + mag + 4x4 pool (4 independent accumulators) + sigmoid^2
        float acc[4] = {0.f, 0.f, 0.f, 0.f};
        #pragma unroll
        for (int i = 0; i < 4; ++i) {
            #pragma unroll
            for (int j = 0; j < 4; ++j) {
                const float a00 = sm6[i][j],     a01 = sm6[i][j + 1],     a02 = sm6[i][j + 2];
                const float a10 = sm6[i + 1][j],                          a12 = sm6[i + 1][j + 2];
                const float a20 = sm6[i + 2][j], a21 = sm6[i + 2][j + 1], a22 = sm6[i + 2][j + 2];
                const float gx = (a02 - a00) + 2.f * (a12 - a10) + (a22 - a20);
                const float gy = (a20 + 2.f * a21 + a22) - (a00 + 2.f * a01 + a02);
                acc[i] += sqrtf(gx * gx + gy * gy + 1e-6f);
            }
        }
        const float down = ((acc[0] + acc[1]) + (acc[2] + acc[3])) * (1.f / 16.f);
        const float x = 5.0f * (down - 0.2f);
        const float sg = 1.f / (1.f + __expf(-x));
        const size_t o = ((size_t)b * OH + (th * TOH + orow)) * OW + (tw * TOW + ocol);
        out[o] = sg * sg;
    }
}

extern "C" void kernel_launch(void* const* d_in, const int* in_sizes, int n_in,
                              void* d_out, int out_size, void* d_ws, size_t ws_size,
                              hipStream_t stream) {
    const float* in = (const float*)d_in[0];
    float* out = (float*)d_out;

    // Gaussian 1D coefficients (separable: outer(g,g)/(sum g)^2), exact in double.
    const double g0 = std::exp(-4.0 / 4.5);  // x=2
    const double g1 = std::exp(-1.0 / 4.5);  // x=1
    const double g2 = 1.0;                   // x=0
    const double S = 2.0 * (g0 + g1) + g2;
    const float gn0 = (float)(g0 / S);
    const float gn1 = (float)(g1 / S);
    const float gn2 = (float)(g2 / S);

    hipLaunchKernelGGL(edge_fused, dim3(B * NTH * NTW), dim3(256), 0, stream,
                       in, out, gn0, gn1, gn2);
}

// Round 12
// 31.755 us; speedup vs baseline: 1.2060x; 1.0715x over previous
//
#include <hip/hip_runtime.h>
#include <cmath>

// Problem constants (fixed by setup_inputs)
constexpr int B = 16, C = 3, H = 544, W = 960;
constexpr int OH = 136, OW = 240;
constexpr size_t HW = (size_t)H * W;

constexpr int TOH = 8, TOW = 30, NTH = 17, NTW = 8, MH = 32, MW = 120;
constexpr int GR = 40;     // gray rows: global rows mh0-4 .. mh0+35 (rows 0,39 pad)
constexpr int GS = 132;    // gray row stride (floats)
constexpr int NT = 5;      // tasks per thread: 40 rows x 32 quads = 1280 = 5*256
constexpr int NBLK = B * NTH * NTW;   // 2176
constexpr int CPX = NBLK / 8;         // 272 logical tiles per XCD (exact)

__global__ __launch_bounds__(256, 2)
void edge_fused(const float* __restrict__ in, float* __restrict__ out,
                float gn0, float gn1, float gn2)
{
    __shared__ float gray[GR * GS];   // 21120 B

    const int tid = threadIdx.x;
    // XCD-aware bijective swizzle: hardware round-robins blockIdx%8 over XCDs;
    // give each XCD 272 consecutive logical tiles (2 whole images) so
    // vertically-adjacent tiles (8-row halo overlap) share one L2.
    const int blk = (blockIdx.x & 7) * CPX + (blockIdx.x >> 3);
    const int tw = blk % NTW;
    const int th = (blk / NTW) % NTH;
    const int b  = blk / (NTW * NTH);
    const int mh0 = th * MH, mw0 = tw * MW;
    const float* inb = in + (size_t)b * C * HW;

    // ---- phase A: load unique RGB region once (batched, unconditional),
    //      convert to gray in LDS. gray[r][lc] <-> global (mh0-4+r, mw0-4+lc).
    float4 Rv[NT], Gv[NT], Bv[NT];
    #pragma unroll
    for (int k = 0; k < NT; ++k) {
        const int idx = tid + 256 * k;
        const int r = idx >> 5;          // /32 quads per row
        const int c = idx & 31;
        int g = mh0 - 4 + r;             // row reflect (always valid)
        g = g < 0 ? -g : (g >= H ? 2 * H - 2 - g : g);
        int gcb = mw0 - 4 + 4 * c;       // col clamp keeps alignment; edge quads fixed below
        gcb = gcb < 0 ? 0 : (gcb > W - 4 ? W - 4 : gcb);
        const float* p = inb + (size_t)g * W + gcb;
        Rv[k] = *reinterpret_cast<const float4*>(p);
        Gv[k] = *reinterpret_cast<const float4*>(p + HW);
        Bv[k] = *reinterpret_cast<const float4*>(p + 2 * HW);
    }
    #pragma unroll
    for (int k = 0; k < NT; ++k) {
        const int idx = tid + 256 * k;
        const int r = idx >> 5;
        const int c = idx & 31;
        float4 g;
        g.x = fmaf(0.2989f, Rv[k].x, fmaf(0.587f, Gv[k].x, 0.114f * Bv[k].x));
        g.y = fmaf(0.2989f, Rv[k].y, fmaf(0.587f, Gv[k].y, 0.114f * Bv[k].y));
        g.z = fmaf(0.2989f, Rv[k].z, fmaf(0.587f, Gv[k].z, 0.114f * Bv[k].z));
        g.w = fmaf(0.2989f, Rv[k].w, fmaf(0.587f, Gv[k].w, 0.114f * Bv[k].w));
        const bool edgeq = (tw == 0 && c == 0) || (tw == NTW - 1 && c == 31);
        if (!edgeq)
            *reinterpret_cast<float4*>(&gray[r * GS + 4 * c]) = g;

        // Column-reflect fixup via same-wave shuffle (no global loads).
        // tw==0: quad 0 locals 0..3 = gray at global cols -4..-1 -> reflect
        //        cols (4,3,2,1) = (lane2.x, lane1.w, lane1.z, lane1.y).
        if (tw == 0) {
            const float nx = __shfl_down(g.x, 1, 32);   // lane c gets lane c+1's x
            if (c == 1)
                *reinterpret_cast<float4*>(&gray[r * GS]) =
                    make_float4(nx, g.w, g.z, g.y);
        } else if (tw == NTW - 1) {
            // quad 31 locals 124..127 = global cols 960..963 -> reflect
            // (958,957,956,955) = (lane30.z, lane30.y, lane30.x, lane29.w).
            const float pw = __shfl_up(g.w, 1, 32);     // lane c gets lane c-1's w
            if (c == 30)
                *reinterpret_cast<float4*>(&gray[r * GS + 4 * 31]) =
                    make_float4(g.z, g.y, g.x, pw);
        }
    }
    __syncthreads();

    // ---- phase B: per LDS row h-blur (12->6), v-accumulate into sm6, then
    //      sobel + pool + sigmoid. ----
    __builtin_amdgcn_s_setprio(1);
    if (tid < TOH * TOW) {
        const int orow = tid / TOW;
        const int ocol = tid - orow * TOW;
        const int lc0 = 4 * ocol;        // gray local col base (reads lc0..lc0+11)
        const int rb = 4 * orow + 1;     // gray local row base (reads rb..rb+9)

        float sm6[6][6];                 // smooth rows i=0..5, cols j=0..5
        #pragma unroll
        for (int i = 0; i < 6; ++i)
            #pragma unroll
            for (int j = 0; j < 6; ++j) sm6[i][j] = 0.f;

        const float gk[5] = {gn0, gn1, gn2, gn1, gn0};
        #pragma unroll
        for (int tr = 0; tr < 10; ++tr) {
            const float* p = &gray[(rb + tr) * GS + lc0];
            const float4 u = *reinterpret_cast<const float4*>(p);
            const float4 v = *reinterpret_cast<const float4*>(p + 4);
            const float4 w = *reinterpret_cast<const float4*>(p + 8);
            const float t12[12] = {u.x, u.y, u.z, u.w, v.x, v.y, v.z, v.w,
                                   w.x, w.y, w.z, w.w};
            float h6[6];                 // h-blurred gray for this row
            #pragma unroll
            for (int j = 0; j < 6; ++j)
                h6[j] = fmaf(gn0, t12[1 + j] + t12[5 + j],
                        fmaf(gn1, t12[2 + j] + t12[4 + j], gn2 * t12[3 + j]));
            #pragma unroll
            for (int i = 0; i < 6; ++i) {
                const int m = tr - i;
                if (m >= 0 && m < 5) {
                    #pragma unroll
                    for (int j = 0; j < 6; ++j)
                        sm6[i][j] = fmaf(gk[m], h6[j], sm6[i][j]);
                }
            }
        }

        // sobel zero-padding: zero smooth outside the image
        #pragma unroll
        for (int i = 0; i < 6; ++i) {
            const int hh = mh0 + 4 * orow - 1 + i;
            const float rm = (hh >= 0 && hh < H) ? 1.f : 0.f;
            #pragma unroll
            for (int j = 0; j < 6; ++j) {
                const int ww = mw0 + 4 * ocol - 1 + j;
                sm6[i][j] *= rm * ((ww >= 0 && ww < W) ? 1.f : 0.f);
            }
        }

        // sobel + mag + 4x4 pool (4 independent accumulators) + sigmoid^2
        float acc[4] = {0.f, 0.f, 0.f, 0.f};
        #pragma unroll
        for (int i = 0; i < 4; ++i) {
            #pragma unroll
            for (int j = 0; j < 4; ++j) {
                const float a00 = sm6[i][j],     a01 = sm6[i][j + 1],     a02 = sm6[i][j + 2];
                const float a10 = sm6[i + 1][j],                          a12 = sm6[i + 1][j + 2];
                const float a20 = sm6[i + 2][j], a21 = sm6[i + 2][j + 1], a22 = sm6[i + 2][j + 2];
                const float gx = (a02 - a00) + 2.f * (a12 - a10) + (a22 - a20);
                const float gy = (a20 + 2.f * a21 + a22) - (a00 + 2.f * a01 + a02);
                acc[i] += sqrtf(gx * gx + gy * gy + 1e-6f);
            }
        }
        const float down = ((acc[0] + acc[1]) + (acc[2] + acc[3])) * (1.f / 16.f);
        const float x = 5.0f * (down - 0.2f);
        const float sg = 1.f / (1.f + __expf(-x));
        const size_t o = ((size_t)b * OH + (th * TOH + orow)) * OW + (tw * TOW + ocol);
        out[o] = sg * sg;
    }
    __builtin_amdgcn_s_setprio(0);
}

extern "C" void kernel_launch(void* const* d_in, const int* in_sizes, int n_in,
                              void* d_out, int out_size, void* d_ws, size_t ws_size,
                              hipStream_t stream) {
    const float* in = (const float*)d_in[0];
    float* out = (float*)d_out;

    // Gaussian 1D coefficients (separable: outer(g,g)/(sum g)^2), exact in double.
    const double g0 = std::exp(-4.0 / 4.5);  // x=2
    const double g1 = std::exp(-1.0 / 4.5);  // x=1
    const double g2 = 1.0;                   // x=0
    const double S = 2.0 * (g0 + g1) + g2;
    const float gn0 = (float)(g0 / S);
    const float gn1 = (float)(g1 / S);
    const float gn2 = (float)(g2 / S);

    hipLaunchKernelGGL(edge_fused, dim3(NBLK), dim3(256), 0, stream,
                       in, out, gn0, gn1, gn2);
}

// Round 13
// 29.297 us; speedup vs baseline: 1.3071x; 1.0839x over previous
//
#include <hip/hip_runtime.h>
#include <cmath>

// Problem constants (fixed by setup_inputs)
constexpr int B = 16, C = 3, H = 544, W = 960;
constexpr int OH = 136, OW = 240;
constexpr size_t HW = (size_t)H * W;

// Wave-autonomous tiling: each 64-lane wave owns an 8x8 output tile.
// No __syncthreads anywhere: all LDS traffic is intra-wave.
constexpr int TRW = 17;                 // output tile rows per image (136/8)
constexpr int TCW = 30;                 // output tile cols per image (240/8)
constexpr int NTILES = B * TRW * TCW;   // 8160 waves
constexpr int WPB = 4;                  // waves per block
constexpr int NBLK = NTILES / WPB;      // 2040 blocks
constexpr int CPX = NBLK / 8;           // 255 blocks per XCD (exact)

constexpr int GRr = 40;                 // gray rows per tile (mh0-4 .. mh0+35)
constexpr int GQ = 10;                  // float4 quads per gray row (40 cols)
constexpr int GS2 = 44;                 // LDS row stride (floats, +4 pad)

__global__ __launch_bounds__(256)
void edge_wave(const float* __restrict__ in, float* __restrict__ out,
               float gn0, float gn1, float gn2)
{
    __shared__ float gray[WPB * GRr * GS2];   // 28160 B

    const int tid  = threadIdx.x;
    const int lane = tid & 63;
    const int wv   = tid >> 6;
    // bijective XCD swizzle: each XCD gets 255 consecutive logical blocks
    const int blk  = ((int)blockIdx.x & 7) * CPX + ((int)blockIdx.x >> 3);
    const int t    = blk * WPB + wv;          // wave-tile id 0..8159
    const int tc   = t % TCW;
    const int tr   = (t / TCW) % TRW;
    const int b    = t / (TCW * TRW);
    const int mh0  = tr * 32, mw0 = tc * 32;
    const float* inb = in + (size_t)b * C * HW;
    float* gw = &gray[wv * GRr * GS2];        // this wave's private region

    // ---- load 400 RGB quads (40 rows x 10 quads): 6 full iters + 16-lane tail.
    //      Loads batched up-front for deep MLP; cols clamped (edges fixed later).
    float4 Rv[7], Gv[7], Bv[7];
    #pragma unroll
    for (int k = 0; k < 6; ++k) {
        const int q = lane + 64 * k;
        const int r = q / GQ, cq = q - r * GQ;
        int g = mh0 - 4 + r;                      // row reflect (always valid)
        g = g < 0 ? -g : (g >= H ? 2 * H - 2 - g : g);
        int gcb = mw0 - 4 + 4 * cq;               // col clamp keeps 16B alignment
        gcb = gcb < 0 ? 0 : (gcb > W - 4 ? W - 4 : gcb);
        const float* p = inb + (size_t)g * W + gcb;
        Rv[k] = *reinterpret_cast<const float4*>(p);
        Gv[k] = *reinterpret_cast<const float4*>(p + HW);
        Bv[k] = *reinterpret_cast<const float4*>(p + 2 * HW);
    }
    if (lane < 16) {
        const int q = lane + 384;
        const int r = q / GQ, cq = q - r * GQ;
        int g = mh0 - 4 + r;
        g = g < 0 ? -g : (g >= H ? 2 * H - 2 - g : g);
        int gcb = mw0 - 4 + 4 * cq;
        gcb = gcb < 0 ? 0 : (gcb > W - 4 ? W - 4 : gcb);
        const float* p = inb + (size_t)g * W + gcb;
        Rv[6] = *reinterpret_cast<const float4*>(p);
        Gv[6] = *reinterpret_cast<const float4*>(p + HW);
        Bv[6] = *reinterpret_cast<const float4*>(p + 2 * HW);
    }

    // ---- convert to gray, write own-wave LDS region ----
    #pragma unroll
    for (int k = 0; k < 6; ++k) {
        const int q = lane + 64 * k;
        const int r = q / GQ, cq = q - r * GQ;
        float4 g;
        g.x = fmaf(0.2989f, Rv[k].x, fmaf(0.587f, Gv[k].x, 0.114f * Bv[k].x));
        g.y = fmaf(0.2989f, Rv[k].y, fmaf(0.587f, Gv[k].y, 0.114f * Bv[k].y));
        g.z = fmaf(0.2989f, Rv[k].z, fmaf(0.587f, Gv[k].z, 0.114f * Bv[k].z));
        g.w = fmaf(0.2989f, Rv[k].w, fmaf(0.587f, Gv[k].w, 0.114f * Bv[k].w));
        *reinterpret_cast<float4*>(&gw[r * GS2 + 4 * cq]) = g;
    }
    if (lane < 16) {
        const int q = lane + 384;
        const int r = q / GQ, cq = q - r * GQ;
        float4 g;
        g.x = fmaf(0.2989f, Rv[6].x, fmaf(0.587f, Gv[6].x, 0.114f * Bv[6].x));
        g.y = fmaf(0.2989f, Rv[6].y, fmaf(0.587f, Gv[6].y, 0.114f * Bv[6].y));
        g.z = fmaf(0.2989f, Rv[6].z, fmaf(0.587f, Gv[6].z, 0.114f * Bv[6].z));
        g.w = fmaf(0.2989f, Rv[6].w, fmaf(0.587f, Gv[6].w, 0.114f * Bv[6].w));
        *reinterpret_cast<float4*>(&gw[r * GS2 + 4 * cq]) = g;
    }

    // intra-wave LDS visibility: wave lockstep + lgkmcnt drain (no s_barrier)
    asm volatile("s_waitcnt lgkmcnt(0)" ::: "memory");
    __builtin_amdgcn_sched_barrier(0);

    // ---- column-reflect fixup (only 2/30 tile columns; wave-uniform branch) ----
    if (tc == 0) {
        // local cols 0..3 = global -4..-1  <- reflect of global 4..1 = local 8..5
        if (lane < GRr) {
            float* g_ = &gw[lane * GS2];
            const float4 v = make_float4(g_[8], g_[7], g_[6], g_[5]);
            *reinterpret_cast<float4*>(g_) = v;
        }
    } else if (tc == TCW - 1) {
        // local 36..39 = global 960..963 <- reflect 958..955 = local 34..31
        if (lane < GRr) {
            float* g_ = &gw[lane * GS2];
            const float4 v = make_float4(g_[34], g_[33], g_[32], g_[31]);
            *reinterpret_cast<float4*>(&g_[36]) = v;
        }
    }
    asm volatile("s_waitcnt lgkmcnt(0)" ::: "memory");
    __builtin_amdgcn_sched_barrier(0);

    // ---- phase B: per-lane output px. h-blur rows (12->6), v-accumulate,
    //      sobel + 4x4 pool + sigmoid^2. ----
    __builtin_amdgcn_s_setprio(1);
    {
        const int or_ = lane >> 3;       // output row within tile (0..7)
        const int oc  = lane & 7;        // output col within tile (0..7)
        const int rb  = 4 * or_ + 1;     // gray local row base (reads rb..rb+9)
        const int lc0 = 4 * oc;          // gray local col base (reads lc0..lc0+11)

        float sm6[6][6];
        #pragma unroll
        for (int i = 0; i < 6; ++i)
            #pragma unroll
            for (int j = 0; j < 6; ++j) sm6[i][j] = 0.f;

        const float gk[5] = {gn0, gn1, gn2, gn1, gn0};
        #pragma unroll
        for (int t2 = 0; t2 < 10; ++t2) {
            const float* p = &gw[(rb + t2) * GS2 + lc0];
            const float4 u = *reinterpret_cast<const float4*>(p);
            const float4 v = *reinterpret_cast<const float4*>(p + 4);
            const float4 w = *reinterpret_cast<const float4*>(p + 8);
            const float t12[12] = {u.x, u.y, u.z, u.w, v.x, v.y, v.z, v.w,
                                   w.x, w.y, w.z, w.w};
            float h6[6];
            #pragma unroll
            for (int j = 0; j < 6; ++j)
                h6[j] = fmaf(gn0, t12[1 + j] + t12[5 + j],
                        fmaf(gn1, t12[2 + j] + t12[4 + j], gn2 * t12[3 + j]));
            #pragma unroll
            for (int i = 0; i < 6; ++i) {
                const int m = t2 - i;
                if (m >= 0 && m < 5) {
                    #pragma unroll
                    for (int j = 0; j < 6; ++j)
                        sm6[i][j] = fmaf(gk[m], h6[j], sm6[i][j]);
                }
            }
        }

        // sobel zero-padding: zero smooth outside the image
        #pragma unroll
        for (int i = 0; i < 6; ++i) {
            const int hh = mh0 + 4 * or_ - 1 + i;
            const float rm = (hh >= 0 && hh < H) ? 1.f : 0.f;
            #pragma unroll
            for (int j = 0; j < 6; ++j) {
                const int ww = mw0 + 4 * oc - 1 + j;
                sm6[i][j] *= rm * ((ww >= 0 && ww < W) ? 1.f : 0.f);
            }
        }

        // sobel + mag + 4x4 pool (4 independent accumulators) + sigmoid^2
        float acc[4] = {0.f, 0.f, 0.f, 0.f};
        #pragma unroll
        for (int i = 0; i < 4; ++i) {
            #pragma unroll
            for (int j = 0; j < 4; ++j) {
                const float a00 = sm6[i][j],     a01 = sm6[i][j + 1],     a02 = sm6[i][j + 2];
                const float a10 = sm6[i + 1][j],                          a12 = sm6[i + 1][j + 2];
                const float a20 = sm6[i + 2][j], a21 = sm6[i + 2][j + 1], a22 = sm6[i + 2][j + 2];
                const float gx = (a02 - a00) + 2.f * (a12 - a10) + (a22 - a20);
                const float gy = (a20 + 2.f * a21 + a22) - (a00 + 2.f * a01 + a02);
                acc[i] += sqrtf(gx * gx + gy * gy + 1e-6f);
            }
        }
        const float down = ((acc[0] + acc[1]) + (acc[2] + acc[3])) * (1.f / 16.f);
        const float x = 5.0f * (down - 0.2f);
        const float sg = 1.f / (1.f + __expf(-x));
        out[((size_t)b * OH + 8 * tr + or_) * OW + 8 * tc + oc] = sg * sg;
    }
    __builtin_amdgcn_s_setprio(0);
}

extern "C" void kernel_launch(void* const* d_in, const int* in_sizes, int n_in,
                              void* d_out, int out_size, void* d_ws, size_t ws_size,
                              hipStream_t stream) {
    const float* in = (const float*)d_in[0];
    float* out = (float*)d_out;

    // Gaussian 1D coefficients (separable: outer(g,g)/(sum g)^2), exact in double.
    const double g0 = std::exp(-4.0 / 4.5);  // x=2
    const double g1 = std::exp(-1.0 / 4.5);  // x=1
    const double g2 = 1.0;                   // x=0
    const double S = 2.0 * (g0 + g1) + g2;
    const float gn0 = (float)(g0 / S);
    const float gn1 = (float)(g1 / S);
    const float gn2 = (float)(g2 / S);

    hipLaunchKernelGGL(edge_wave, dim3(NBLK), dim3(256), 0, stream,
                       in, out, gn0, gn1, gn2);
}